// Round 6
// baseline (184.389 us; speedup 1.0000x reference)
//
#include <hip/hip_runtime.h>
#include <hip/hip_bf16.h>
#include <math.h>

// Shapes: B=8, T1=512, T2=128, LA=128, E=64, G=3E=192, DL=256
#define Bn 8
#define T1n 512
#define T2n 128
#define En 64
#define Gn 192
#define DLn 256
#define XGP 204   // padded LDS row (bf16 elems): 4*408B row-quad stride -> bank shift 24, conflict-free D-scatter

typedef __attribute__((ext_vector_type(8))) short short8;
typedef __attribute__((ext_vector_type(4))) float float4v;

__device__ __forceinline__ float fast_rcp(float x) { return __builtin_amdgcn_rcpf(x); }

// round-to-nearest-even f32 -> bf16 bits
__device__ __forceinline__ unsigned short f32_to_bf16(float v) {
    unsigned u = __builtin_bit_cast(unsigned, v);
    u += 0x7FFFu + ((u >> 16) & 1u);
    return (unsigned short)(u >> 16);
}
__device__ __forceinline__ float bf16_to_f32(unsigned short s) {
    unsigned u = ((unsigned)s) << 16;
    return __builtin_bit_cast(float, u);
}

// ---------------------------------------------------------------------------
// K3: self-contained GRU scan. 16 blocks = (b, dir), ONE wave (64 threads).
// Phase 1: xg = emb(cs) @ K + b[0] via MFMA (M=128 t's, N=192 gates, K=64),
//          stored bf16 in LDS (padded rows). 16 m-tiles... 8 mt x 12 nt x 2 kt.
// Phase 2: 128-step scan; per step h.R via 24 MFMA (A = h bcast over 16 rows),
//          all operands LDS/register-resident: NO global loads in the loop.
// Single-wave: no barriers; LDS ordering via in-order DS + lgkmcnt.
// ---------------------------------------------------------------------------
__global__ __launch_bounds__(64) void k_scan(const int* __restrict__ char_seq,
                                             const float* __restrict__ emb_table,
                                             const float* __restrict__ Kf,
                                             const float* __restrict__ bf,
                                             const float* __restrict__ Kb,
                                             const float* __restrict__ bb,
                                             const float* __restrict__ Rf,
                                             const float* __restrict__ Rb,
                                             float* __restrict__ ctx) {
    int blk = blockIdx.x;             // 0..15
    int b = blk & 7, d = blk >> 3;
    int lane = threadIdx.x;           // 0..63
    int quad = lane >> 4, col = lane & 15;

    const float* Km   = d ? Kb : Kf;
    const float* bias = d ? bb : bf;  // [2][192]
    const float* R    = d ? Rb : Rf;

    // mask bits in SGPRs
    unsigned long long mlo = __ballot(char_seq[b * T2n + lane] != 0);
    unsigned long long mhi = __ballot(char_seq[b * T2n + 64 + lane] != 0);

    __shared__ unsigned short xg_l[T2n * XGP];        // ~51 KB
    __shared__ __align__(16) unsigned short hb[En];   // h in bf16, 128 B

    // ---------------- phase 1: xg into LDS ----------------
    {
        // K fragments: B[k][n], n=nt*16+col, k=kt*32+quad*8+j
        short8 Kfrag[12][2];
        #pragma unroll
        for (int nt = 0; nt < 12; ++nt)
            #pragma unroll
            for (int kt = 0; kt < 2; ++kt) {
                short8 f;
                #pragma unroll
                for (int j = 0; j < 8; ++j)
                    f[j] = (short)f32_to_bf16(Km[(kt * 32 + quad * 8 + j) * Gn + nt * 16 + col]);
                Kfrag[nt][kt] = f;
            }
        float b0v[12];
        #pragma unroll
        for (int nt = 0; nt < 12; ++nt) b0v[nt] = bias[nt * 16 + col];

        #pragma unroll
        for (int mt = 0; mt < 8; ++mt) {
            // A-frag: A[m][k] = emb_table[cs[mt*16+m]][k], m=col, k=kt*32+quad*8+j
            int cs = char_seq[b * T2n + mt * 16 + col];
            const float4* e4 = (const float4*)(emb_table + (size_t)cs * En);
            float4 e0 = e4[quad * 2], e1 = e4[quad * 2 + 1];
            float4 e2 = e4[8 + quad * 2], e3 = e4[8 + quad * 2 + 1];
            short8 a0, a1;
            a0[0] = (short)f32_to_bf16(e0.x); a0[1] = (short)f32_to_bf16(e0.y);
            a0[2] = (short)f32_to_bf16(e0.z); a0[3] = (short)f32_to_bf16(e0.w);
            a0[4] = (short)f32_to_bf16(e1.x); a0[5] = (short)f32_to_bf16(e1.y);
            a0[6] = (short)f32_to_bf16(e1.z); a0[7] = (short)f32_to_bf16(e1.w);
            a1[0] = (short)f32_to_bf16(e2.x); a1[1] = (short)f32_to_bf16(e2.y);
            a1[2] = (short)f32_to_bf16(e2.z); a1[3] = (short)f32_to_bf16(e2.w);
            a1[4] = (short)f32_to_bf16(e3.x); a1[5] = (short)f32_to_bf16(e3.y);
            a1[6] = (short)f32_to_bf16(e3.z); a1[7] = (short)f32_to_bf16(e3.w);
            float4v acc[12];
            #pragma unroll
            for (int nt = 0; nt < 12; ++nt) {
                float4v z4 = {0.f, 0.f, 0.f, 0.f};
                z4 = __builtin_amdgcn_mfma_f32_16x16x32_bf16(a1, Kfrag[nt][1], z4, 0, 0, 0);
                acc[nt] = __builtin_amdgcn_mfma_f32_16x16x32_bf16(a0, Kfrag[nt][0], z4, 0, 0, 0);
            }
            // D: row = quad*4+r (t within tile), col n = nt*16+col
            #pragma unroll
            for (int nt = 0; nt < 12; ++nt)
                #pragma unroll
                for (int r = 0; r < 4; ++r)
                    xg_l[(mt * 16 + quad * 4 + r) * XGP + nt * 16 + col] =
                        f32_to_bf16(acc[nt][r] + b0v[nt]);
        }
    }

    // ---------------- phase 2: the scan ----------------
    // R fragments (loaded after Kfrag is dead to cap VGPR pressure)
    short8 Bfrag[12][2];
    #pragma unroll
    for (int nt = 0; nt < 12; ++nt)
        #pragma unroll
        for (int kt = 0; kt < 2; ++kt) {
            short8 f;
            #pragma unroll
            for (int j = 0; j < 8; ++j)
                f[j] = (short)f32_to_bf16(R[(kt * 32 + quad * 8 + j) * Gn + nt * 16 + col]);
            Bfrag[nt][kt] = f;
        }
    float bz = bias[Gn + lane], br = bias[Gn + En + lane], bh = bias[Gn + 2 * En + lane];

    hb[lane] = 0;
    float hreg = 0.f, y = 0.f;
    float* ctxb = ctx + (size_t)b * T2n * 128 + d * En;
    int i0 = d ? (T2n - 1) : 0;
    int istep = d ? -1 : 1;
    bool q1 = (quad & 1) != 0, q2 = (quad & 2) != 0;
    const short8* ap = (const short8*)hb;

    for (int step = 0; step < T2n; ++step) {
        int idx = i0 + istep * step;
        // x gates from LDS (bf16); lane-contiguous -> conflict-free
        int xb = idx * XGP + lane;
        unsigned short xzs = xg_l[xb];
        unsigned short xrs = xg_l[xb + 64];
        unsigned short xhs = xg_l[xb + 128];
        // A fragments of h
        short8 a0 = ap[quad];
        short8 a1 = ap[4 + quad];
        float4v acc[12];
        #pragma unroll
        for (int nt = 0; nt < 12; ++nt) {
            float4v z4 = {0.f, 0.f, 0.f, 0.f};
            z4 = __builtin_amdgcn_mfma_f32_16x16x32_bf16(a1, Bfrag[nt][1], z4, 0, 0, 0);
            acc[nt] = __builtin_amdgcn_mfma_f32_16x16x32_bf16(a0, Bfrag[nt][0], z4, 0, 0, 0);
        }
        // select this lane's rz/rr/rh (tile nt = quad(+4,+8), col = lane&15)
        float z01 = q1 ? acc[1].x : acc[0].x;
        float z23 = q1 ? acc[3].x : acc[2].x;
        float rz  = (q2 ? z23 : z01) + bz;
        float r01 = q1 ? acc[5].x : acc[4].x;
        float r23 = q1 ? acc[7].x : acc[6].x;
        float rr  = (q2 ? r23 : r01) + br;
        float h01 = q1 ? acc[9].x : acc[8].x;
        float h23 = q1 ? acc[11].x : acc[10].x;
        float rh  = (q2 ? h23 : h01) + bh;
        // gates
        float xz = bf16_to_f32(xzs), xr = bf16_to_f32(xrs), xh = bf16_to_f32(xhs);
        float z = fast_rcp(1.f + __expf(-(xz + rz)));
        float r = fast_rcp(1.f + __expf(-(xr + rr)));
        float a = xh + r * rh;
        float hh = 1.f - 2.f * fast_rcp(1.f + __expf(2.f * a));
        float hn = hh + z * (hreg - hh);
        bool m = (idx < 64) ? ((mlo >> idx) & 1ull) : ((mhi >> (idx - 64)) & 1ull);
        if (m) { hreg = hn; y = hn; }
        ctxb[idx * 128 + lane] = y;       // fire-and-forget global store
        hb[lane] = f32_to_bf16(hreg);     // same-wave LDS; lgkmcnt-ordered
    }
}

// ---------------------------------------------------------------------------
// K4: per (b,s): P0/P1 = ctx_row @ W1[tap], then
//   A = P0@W20, Cm = P1@W21, Bm = P1@W20 + P0@W21, sC = ctx_row . w_c,
//   plus 4 sL dot-products per block (sL[b][t] = lstm[b][t] . w_char[0:256]).
// ---------------------------------------------------------------------------
__global__ __launch_bounds__(128) void k_ctxw(const float* __restrict__ ctx,
                                              const float* __restrict__ conv1_w,
                                              const float* __restrict__ conv2_w,
                                              const float* __restrict__ w_char,
                                              const float* __restrict__ lstm,
                                              float* __restrict__ Am,
                                              float* __restrict__ Bm,
                                              float* __restrict__ Cm,
                                              float* __restrict__ sC,
                                              float* __restrict__ sL) {
    int bs = blockIdx.x;              // b*128+s
    int tid = threadIdx.x;            // 0..127
    // --- fused sL: block bs computes sL[bs*4 .. bs*4+4) ---
    {
        int wv = tid >> 6, lane = tid & 63;
        const float4* wl = (const float4*)w_char;
        #pragma unroll
        for (int q = 0; q < 2; ++q) {
            int bt = bs * 4 + wv * 2 + q;
            const float4* row = (const float4*)(lstm + (size_t)bt * DLn);
            float4 r4 = row[lane];
            float4 w4 = wl[lane];
            float s = r4.x * w4.x + r4.y * w4.y + r4.z * w4.z + r4.w * w4.w;
            #pragma unroll
            for (int off = 32; off; off >>= 1) s += __shfl_down(s, off);
            if (lane == 0) sL[bt] = s;
        }
    }
    __shared__ float crow[128];
    __shared__ float p0[En], p1[En];
    crow[tid] = ctx[(size_t)bs * 128 + tid];
    __syncthreads();
    if (tid < 64) {
        float s = crow[tid] * w_char[DLn + tid] + crow[64 + tid] * w_char[DLn + 64 + tid];
        #pragma unroll
        for (int off = 32; off; off >>= 1) s += __shfl_down(s, off);
        if (tid == 0) sC[bs] = s;
    }
    int tap = tid >> 6, o = tid & 63;
    const float* W = conv1_w + tap * 128 * En;
    float acc = 0.f;
    #pragma unroll
    for (int c = 0; c < 128; ++c) acc = fmaf(crow[c], W[c * En + o], acc);
    if (tap == 0) p0[o] = acc; else p1[o] = acc;
    __syncthreads();
    const float* W20 = conv2_w;            // [64][64]
    const float* W21 = conv2_w + En * En;
    if (tid < 64) {
        float a = 0.f, cm = 0.f;
        #pragma unroll
        for (int c = 0; c < En; ++c) {
            a  = fmaf(p0[c], W20[c * En + tid], a);
            cm = fmaf(p1[c], W21[c * En + tid], cm);
        }
        Am[(size_t)bs * En + tid] = a;
        Cm[(size_t)bs * En + tid] = cm;
    } else {
        int o2 = tid - 64;
        float bacc = 0.f;
        #pragma unroll
        for (int c = 0; c < En; ++c) {
            bacc = fmaf(p1[c], W20[c * En + o2], bacc);
            bacc = fmaf(p0[c], W21[c * En + o2], bacc);
        }
        Bm[(size_t)bs * En + o2] = bacc;
    }
}

// ---------------------------------------------------------------------------
// K5: per (b, 8-t tile): score rows -> char_weights; then
//   fe[b,t,o] = max_s ( sc[s]*A[s,o] + sc[s+1]*Bm[s+1,o] + sc[s+2]*Cm[s+2,o] + bb2[o] )
// ---------------------------------------------------------------------------
__global__ __launch_bounds__(128) void k_final(const float* __restrict__ sL,
                                               const float* __restrict__ sC,
                                               const float* __restrict__ w_char,
                                               const float* __restrict__ b_char,
                                               const float* __restrict__ conv1_b,
                                               const float* __restrict__ conv2_w,
                                               const float* __restrict__ conv2_b,
                                               const float* __restrict__ Am,
                                               const float* __restrict__ Bm,
                                               const float* __restrict__ Cm,
                                               float* __restrict__ fe,
                                               float* __restrict__ cw) {
    int blk = blockIdx.x;             // b(3b) x ttile(6b)
    int b = blk >> 6, ttile = blk & 63;
    int t0 = ttile * 8;
    int tid = threadIdx.x;            // 0..127
    float w_t = w_char[DLn + 128], w_i = w_char[DLn + 129], bc = b_char[0];
    __shared__ float sc8[8][T2n];
    {
        int s = tid;
        float sCs = sC[b * T2n + s] + w_i * (float)s + bc;
        #pragma unroll
        for (int tt = 0; tt < 8; ++tt) {
            int t = t0 + tt;
            float v = sL[b * T1n + t] + sCs + w_t * (float)t;
            sc8[tt][s] = v;
            cw[((size_t)(b * T1n + t)) * T2n + s] = v;
        }
    }
    int o = tid & 63, p = tid >> 6;
    float bb2 = conv2_b[o];
    #pragma unroll
    for (int c = 0; c < En; ++c)
        bb2 += conv1_b[c] * (conv2_w[c * En + o] + conv2_w[En * En + c * En + o]);
    __syncthreads();

    float acc[8];
    #pragma unroll
    for (int tt = 0; tt < 8; ++tt) acc[tt] = -__builtin_inff();
    const float* Ab = Am + (size_t)(b * T2n) * En + o;
    const float* Bb = Bm + (size_t)(b * T2n) * En + o;
    const float* Cb = Cm + (size_t)(b * T2n) * En + o;
    for (int s = p; s < T2n - 2; s += 2) {
        float a  = Ab[s * En];
        float bm = Bb[(s + 1) * En];
        float cm = Cb[(s + 2) * En];
        #pragma unroll
        for (int tt = 0; tt < 8; ++tt) {
            float v = fmaf(sc8[tt][s], a,
                      fmaf(sc8[tt][s + 1], bm,
                      fmaf(sc8[tt][s + 2], cm, bb2)));
            acc[tt] = fmaxf(acc[tt], v);
        }
    }
    __shared__ float red[64][9];
    if (p == 1) {
        #pragma unroll
        for (int tt = 0; tt < 8; ++tt) red[o][tt] = acc[tt];
    }
    __syncthreads();
    if (p == 0) {
        #pragma unroll
        for (int tt = 0; tt < 8; ++tt) {
            float v = fmaxf(acc[tt], red[o][tt]);
            fe[((size_t)(b * T1n + t0 + tt)) * En + o] = v;
        }
    }
}

// ---------------------------------------------------------------------------
extern "C" void kernel_launch(void* const* d_in, const int* in_sizes, int n_in,
                              void* d_out, int out_size, void* d_ws, size_t ws_size,
                              hipStream_t stream) {
    const float* lstm      = (const float*)d_in[0];
    const int*   char_seq  = (const int*)d_in[1];
    const float* emb_table = (const float*)d_in[2];
    const float* Kf        = (const float*)d_in[3];
    const float* Rf        = (const float*)d_in[4];
    const float* bf        = (const float*)d_in[5];
    const float* Kb        = (const float*)d_in[6];
    const float* Rb        = (const float*)d_in[7];
    const float* bb        = (const float*)d_in[8];
    const float* w_char    = (const float*)d_in[9];
    const float* b_char    = (const float*)d_in[10];
    const float* conv1_w   = (const float*)d_in[11];
    const float* conv1_b   = (const float*)d_in[12];
    const float* conv2_w   = (const float*)d_in[13];
    const float* conv2_b   = (const float*)d_in[14];

    float* out = (float*)d_out;
    float* fe = out;                             // 8*512*64 = 262144
    float* cw = out + Bn * T1n * En;             // 8*512*128 = 524288

    float* ws  = (float*)d_ws;
    float* ctx = ws;                             // 8*128*128 = 131072
    float* sC  = ctx + Bn * T2n * 128;           // 1024
    float* sL  = sC + Bn * T2n;                  // 4096
    float* Am  = sL + Bn * T1n;                  // 65536
    float* Bm  = Am + Bn * T2n * En;             // 65536
    float* Cm  = Bm + Bn * T2n * En;             // 65536

    k_scan<<<16, 64, 0, stream>>>(char_seq, emb_table, Kf, bf, Kb, bb, Rf, Rb, ctx);
    k_ctxw<<<Bn * T2n, 128, 0, stream>>>(ctx, conv1_w, conv2_w, w_char, lstm,
                                         Am, Bm, Cm, sC, sL);
    k_final<<<(Bn * T1n) / 8, 128, 0, stream>>>(sL, sC, w_char, b_char, conv1_b,
                                                conv2_w, conv2_b, Am, Bm, Cm, fe, cw);
}